// Round 8
// baseline (183.698 us; speedup 1.0000x reference)
//
#include <hip/hip_runtime.h>
#include <hip/hip_cooperative_groups.h>

namespace cg = cooperative_groups;

// Problem constants (fixed by the reference).
#define BB   32
#define TT   2048
#define FF   512
#define KK   1024
#define DD   512
#define NCMAX 512        // max active timesteps: g>=0.05 -> g*(1-g)^c >= 1e-12 needs c <= 481
#define LN_EPS 1e-5f
#define WCUT 1e-12f      // drop terms with EMA weight < 1e-12 (bounded err ~5e-11 << 5.8e-2 thr)

#define NBLK 256         // cooperative grid: 1 block/CU guaranteed co-resident
#define NTHR 512         // 8 waves

typedef __attribute__((ext_vector_type(8))) short bf16x8;
typedef __attribute__((ext_vector_type(4))) float f32x4;

// g = clip(sigmoid(w1*cos(t1)cos(p1) + w2*cos(t2)cos(p2) + b_g), 0.05, 0.75)
__device__ __forceinline__ float compute_g(const float* th1, const float* ph1,
                                           const float* th2, const float* ph2,
                                           const float* w1, const float* w2,
                                           const float* bg) {
    float z1 = cosf(*th1) * cosf(*ph1);
    float z2 = cosf(*th2) * cosf(*ph2);
    float s  = (*w1) * z1 + (*w2) * z2 + (*bg);
    float sg = 1.0f / (1.0f + expf(-s));
    return fminf(fmaxf(sg, 0.05f), 0.75f);
}

// fp32 -> bf16 bits, round-to-nearest-even
__device__ __forceinline__ ushort f2bf(float x) {
    unsigned u = __float_as_uint(x);
    u += 0x7FFFu + ((u >> 16) & 1u);
    return (ushort)(u >> 16);
}

// LDS union across phases (max 48 KB)
union Smem {
    struct { int cnt4[8]; } p0;
    struct { ushort As[2][4096]; ushort Bs[2][4096]; } p1;        // 32 KB (2 tiles)
    struct { float xs[2][8][256]; float red[2][4][8][128]; } p2;  // 48 KB (2 items)
    struct { float hred[8][DD]; } p3;                             // 16 KB
};

// ============================ the single fused kernel ============================
// P1: CT = (Ww.Pw)^T via bf16 MFMA (32 blocks x 2 independent 64x64 tiles; verified
//     octet-major XOR-slot LDS layout; 2-deep register prefetch pipeline).
//     Block 0 also builds the EMA weight table wj[c]=g*(1-g)^c and n_active.
// P2: base[fh][c][b][d] = x-row . CT-half (work items (c,fh,bg,dt), act-guarded).
// P3: LayerNorm + EMA-weighted reduction -> out. alpha*cal_scalar is d-constant and
//     cancels exactly in LN -> never computed.
__global__ __launch_bounds__(NTHR, 1) void fused_all(
    const float* __restrict__ x,   const float* __restrict__ Pw,
    const float* __restrict__ Ww,  const float* __restrict__ Wb,
    const float* __restrict__ bvec,const float* __restrict__ lng,
    const float* __restrict__ lnb,
    const float* th1, const float* ph1, const float* th2, const float* ph2,
    const float* w1p, const float* w2p, const float* bgp,
    float* __restrict__ CT, float* __restrict__ wj, int* __restrict__ nact,
    float* __restrict__ base, float* __restrict__ out) {

    __shared__ Smem sm;
    const int tid  = threadIdx.x;
    const int bid  = blockIdx.x;
    const int half = tid >> 8;       // 0/1: two independent 256-thread units
    const int ltid = tid & 255;
    cg::grid_group gg = cg::this_grid();

    // ---------------- P0: wj table + n_active (block 0 only) ----------------
    if (bid == 0) {
        const float g   = compute_g(th1, ph1, th2, ph2, w1p, w2p, bgp);
        const float omg = 1.0f - g;
        const float w0  = g * powf(omg, (float)tid);   // tid 0..511 covers all c
        wj[tid] = w0;
        const unsigned long long m = __ballot(w0 >= WCUT);
        if ((tid & 63) == 0) sm.p0.cnt4[tid >> 6] = __popcll(m);
        __syncthreads();
        if (tid == 0) {
            int s = 0;
            #pragma unroll
            for (int i = 0; i < 8; ++i) s += sm.p0.cnt4[i];
            *nact = s;   // == cutoff index (wj monotone decreasing)
        }
        __syncthreads();   // cnt4 region reused by As below
    }

    // ---------------- P1: MFMA weight merge (blocks 0..31, 2 tiles each) ----------------
    if (bid < 32) {
        const int tile = bid * 2 + half;        // 0..63
        const int d0   = (tile >> 3) * 64;
        const int f0   = (tile & 7) * 64;
        const int wave = ltid >> 6;
        const int lane = ltid & 63;
        const int wm2  = wave >> 1;             // d-half of tile
        const int wn2  = wave & 1;              // f-half of tile
        const int lg   = lane >> 4;             // k-octet group
        const int ll   = lane & 15;             // free-index lane
        const int cw   = ltid & 15;             // staging col group
        const int rq   = ltid >> 4;             // staging row group

        ushort* As_ = sm.p1.As[half];
        ushort* Bs_ = sm.p1.Bs[half];

        f32x4 acc00 = {0.f,0.f,0.f,0.f}, acc01 = {0.f,0.f,0.f,0.f};
        f32x4 acc10 = {0.f,0.f,0.f,0.f}, acc11 = {0.f,0.f,0.f,0.f};
        float4 wwA[4], paA[2], pbA[2];
        float4 wwB[4], paB[2], pbB[2];

#define WM_STAGE(WW, PA, PB, kkv) do {                                                   \
        _Pragma("unroll")                                                                \
        for (int i = 0; i < 4; ++i)                                                      \
            WW[i] = *(const float4*)(Ww + (size_t)(d0 + rq + i * 16) * KK + (kkv) + cw * 4); \
        _Pragma("unroll")                                                                \
        for (int i = 0; i < 2; ++i) {                                                    \
            const int kr = (rq + i * 16) * 2;                                            \
            PA[i] = *(const float4*)(Pw + (size_t)((kkv) + kr)     * FF + f0 + cw * 4);  \
            PB[i] = *(const float4*)(Pw + (size_t)((kkv) + kr + 1) * FF + f0 + cw * 4);  \
        }                                                                                \
    } while (0)

#define WM_WRITE(WW, PA, PB) do {                                                        \
        const int qa = cw >> 1, ha = cw & 1, qa3 = qa & 3;                               \
        _Pragma("unroll")                                                                \
        for (int i = 0; i < 4; ++i) {                                                    \
            const int r = rq + i * 16;                                                   \
            ushort4 b_;                                                                  \
            b_.x = f2bf(WW[i].x); b_.y = f2bf(WW[i].y);                                  \
            b_.z = f2bf(WW[i].z); b_.w = f2bf(WW[i].w);                                  \
            *(ushort4*)&As_[qa * 512 + ((r ^ qa3) << 3) + ha * 4] = b_;                  \
        }                                                                                \
        _Pragma("unroll")                                                                \
        for (int i = 0; i < 2; ++i) {                                                    \
            const int kr = (rq + i * 16) * 2;                                            \
            const int q = kr >> 3, jj = kr & 7, q3 = q & 3;                              \
            const float fa_[4] = {PA[i].x, PA[i].y, PA[i].z, PA[i].w};                   \
            const float fb_[4] = {PB[i].x, PB[i].y, PB[i].z, PB[i].w};                   \
            _Pragma("unroll")                                                            \
            for (int e = 0; e < 4; ++e) {                                                \
                ushort2 p_; p_.x = f2bf(fa_[e]); p_.y = f2bf(fb_[e]);                    \
                *(ushort2*)&Bs_[q * 512 + (((cw * 4 + e) ^ q3) << 3) + jj] = p_;         \
            }                                                                            \
        }                                                                                \
    } while (0)

#define WM_MFMA() do {                                                                   \
        _Pragma("unroll")                                                                \
        for (int ks = 0; ks < 2; ++ks) {                                                 \
            const int bofs = (ks * 4 + lg) * 512;                                        \
            const bf16x8 af0 = *(const bf16x8*)&As_[bofs + (((wm2 * 32 +  0 + ll) ^ lg) << 3)]; \
            const bf16x8 af1 = *(const bf16x8*)&As_[bofs + (((wm2 * 32 + 16 + ll) ^ lg) << 3)]; \
            const bf16x8 bg0 = *(const bf16x8*)&Bs_[bofs + (((wn2 * 32 +  0 + ll) ^ lg) << 3)]; \
            const bf16x8 bg1 = *(const bf16x8*)&Bs_[bofs + (((wn2 * 32 + 16 + ll) ^ lg) << 3)]; \
            acc00 = __builtin_amdgcn_mfma_f32_16x16x32_bf16(af0, bg0, acc00, 0, 0, 0);   \
            acc01 = __builtin_amdgcn_mfma_f32_16x16x32_bf16(af0, bg1, acc01, 0, 0, 0);   \
            acc10 = __builtin_amdgcn_mfma_f32_16x16x32_bf16(af1, bg0, acc10, 0, 0, 0);   \
            acc11 = __builtin_amdgcn_mfma_f32_16x16x32_bf16(af1, bg1, acc11, 0, 0, 0);   \
        }                                                                                \
    } while (0)

        WM_STAGE(wwA, paA, pbA, 0);
        WM_STAGE(wwB, paB, pbB, 64);
        for (int kk = 0; kk < KK; kk += 128) {
            WM_WRITE(wwA, paA, pbA);
            __syncthreads();
            if (kk + 128 < KK) WM_STAGE(wwA, paA, pbA, kk + 128);  // 2-deep prefetch
            WM_MFMA();
            __syncthreads();
            WM_WRITE(wwB, paB, pbB);
            __syncthreads();
            if (kk + 192 < KK) WM_STAGE(wwB, paB, pbB, kk + 192);
            WM_MFMA();
            __syncthreads();
        }
#undef WM_STAGE
#undef WM_WRITE
#undef WM_MFMA

        // epilogue: CT[f][d] (D-layout verified: col=lane&15 -> f, row=(lane>>4)*4+reg -> d)
        const int fb = f0 + wn2 * 32 + ll;
        const int db = d0 + wm2 * 32 + lg * 4;
        *(float4*)(CT + (size_t)(fb     ) * DD + db     ) = make_float4(acc00[0], acc00[1], acc00[2], acc00[3]);
        *(float4*)(CT + (size_t)(fb + 16) * DD + db     ) = make_float4(acc01[0], acc01[1], acc01[2], acc01[3]);
        *(float4*)(CT + (size_t)(fb     ) * DD + db + 16) = make_float4(acc10[0], acc10[1], acc10[2], acc10[3]);
        *(float4*)(CT + (size_t)(fb + 16) * DD + db + 16) = make_float4(acc11[0], acc11[1], acc11[2], acc11[3]);
    }

    __threadfence();
    gg.sync();   // CT, wj, nact visible grid-wide

    // ---------------- P2: base GEMM over work items (c, fh, bg, dt) ----------------
    {
        const int nv     = *nact;
        const int nitems = nv * 32;                       // 32 sub-items per active c
        const int jmax   = (nitems + NBLK * 2 - 1) / (NBLK * 2);

        float (*xs)[256]       = sm.p2.xs[half];
        float (*red)[8][128]   = sm.p2.red[half];
        const int fs = (ltid >> 5) & 3;
        const int rg = ltid >> 7;
        const int dl = ltid & 31;

        for (int j = 0; j < jmax; ++j) {
            const int item = j * NBLK * 2 + bid * 2 + half;
            const bool act = item < nitems;
            const int c  = item >> 5;
            const int fh = (item >> 4) & 1;
            const int bg = (item >> 2) & 3;
            const int dt = item & 3;
            const int t  = TT - 1 - c;

            if (act) {   // stage 8 x rows (f-half), coalesced float4
                for (int i = ltid; i < 8 * 256 / 4; i += 256) {
                    const int r  = i >> 6;
                    const int f4 = (i & 63) * 4;
                    *(float4*)&xs[r][f4] =
                        *(const float4*)(x + ((size_t)(bg * 8 + r) * TT + t) * FF + fh * 256 + f4);
                }
            }
            __syncthreads();

            if (act) {
                float4 acc[4];
                #pragma unroll
                for (int r = 0; r < 4; ++r) acc[r] = make_float4(0.f, 0.f, 0.f, 0.f);
                const float* ctp = CT + (size_t)(fh * 256 + fs * 64) * DD + dt * 128 + dl * 4;
                #pragma unroll 4
                for (int f = 0; f < 64; f += 4) {
                    const float4 cv0 = *(const float4*)(ctp + (size_t)(f + 0) * DD);
                    const float4 cv1 = *(const float4*)(ctp + (size_t)(f + 1) * DD);
                    const float4 cv2 = *(const float4*)(ctp + (size_t)(f + 2) * DD);
                    const float4 cv3 = *(const float4*)(ctp + (size_t)(f + 3) * DD);
                    #pragma unroll
                    for (int r = 0; r < 4; ++r) {
                        const float4 xv = *(const float4*)&xs[rg * 4 + r][fs * 64 + f];  // LDS b128 broadcast
                        acc[r].x += xv.x * cv0.x + xv.y * cv1.x + xv.z * cv2.x + xv.w * cv3.x;
                        acc[r].y += xv.x * cv0.y + xv.y * cv1.y + xv.z * cv2.y + xv.w * cv3.y;
                        acc[r].z += xv.x * cv0.z + xv.y * cv1.z + xv.z * cv2.z + xv.w * cv3.z;
                        acc[r].w += xv.x * cv0.w + xv.y * cv1.w + xv.z * cv2.w + xv.w * cv3.w;
                    }
                }
                #pragma unroll
                for (int r = 0; r < 4; ++r)
                    *(float4*)&red[fs][rg * 4 + r][dl * 4] = acc[r];
            }
            __syncthreads();

            if (act) {   // reduce over 4 f-slices; write raw base part
                const int r2 = ltid >> 5;
                float4 s = make_float4(0.f, 0.f, 0.f, 0.f);
                #pragma unroll
                for (int q = 0; q < 4; ++q) {
                    const float4 v = *(const float4*)&red[q][r2][dl * 4];
                    s.x += v.x; s.y += v.y; s.z += v.z; s.w += v.w;
                }
                *(float4*)(base + (((size_t)fh * NCMAX + c) * BB + bg * 8 + r2) * DD + dt * 128 + dl * 4) = s;
            }
            __syncthreads();   // protect xs/red for next item
        }
    }

    __threadfence();
    gg.sync();   // base visible grid-wide

    // ---------------- P3: LN + EMA + reduce (blocks 0..31, one batch each) ----------------
    if (bid < BB) {
        const int b  = bid;
        const int w  = tid >> 6;
        const int l  = tid & 63;
        const int nv = *nact;

        float ga[8], be[8], bi[8];
        #pragma unroll
        for (int i = 0; i < 8; ++i) {
            ga[i] = lng[l * 8 + i];
            be[i] = lnb[l * 8 + i];
            bi[i] = Wb[l * 8 + i] + bvec[l * 8 + i];
        }

        float hacc[8] = {0.f, 0.f, 0.f, 0.f, 0.f, 0.f, 0.f, 0.f};

        for (int c = w; c < nv; c += 8) {
            const float wjc = wj[c];
            const float* bp0 = base + ((size_t)c * BB + b) * DD + l * 8;
            const float* bp1 = bp0 + (size_t)NCMAX * BB * DD;
            const float4 u0 = *(const float4*)(bp0);
            const float4 u1 = *(const float4*)(bp0 + 4);
            const float4 q0 = *(const float4*)(bp1);
            const float4 q1 = *(const float4*)(bp1 + 4);
            float vv[8];
            vv[0] = u0.x + q0.x + bi[0]; vv[1] = u0.y + q0.y + bi[1];
            vv[2] = u0.z + q0.z + bi[2]; vv[3] = u0.w + q0.w + bi[3];
            vv[4] = u1.x + q1.x + bi[4]; vv[5] = u1.y + q1.y + bi[5];
            vv[6] = u1.z + q1.z + bi[6]; vv[7] = u1.w + q1.w + bi[7];

            float S = 0.f, Q = 0.f;
            #pragma unroll
            for (int i = 0; i < 8; ++i) { S += vv[i]; Q += vv[i] * vv[i]; }
            #pragma unroll
            for (int off = 32; off >= 1; off >>= 1) {
                S += __shfl_xor(S, off);
                Q += __shfl_xor(Q, off);
            }
            const float mu   = S * (1.0f / DD);
            const float rstd = rsqrtf(Q * (1.0f / DD) - mu * mu + LN_EPS);
            #pragma unroll
            for (int i = 0; i < 8; ++i)
                hacc[i] += wjc * ((vv[i] - mu) * rstd * ga[i] + be[i]);
        }

        #pragma unroll
        for (int i = 0; i < 8; ++i) sm.p3.hred[w][l * 8 + i] = hacc[i];
        __syncthreads();

        {
            const int d = tid;
            float s = 0.f;
            #pragma unroll
            for (int q = 0; q < 8; ++q) s += sm.p3.hred[q][d];
            out[(size_t)b * DD + d] = s;
        }
    }
}

extern "C" void kernel_launch(void* const* d_in, const int* in_sizes, int n_in,
                              void* d_out, int out_size, void* d_ws, size_t ws_size,
                              hipStream_t stream) {
    const float* x   = (const float*)d_in[0];
    const float* Pw  = (const float*)d_in[1];
    const float* Ww  = (const float*)d_in[2];
    const float* Wb  = (const float*)d_in[3];
    const float* bv  = (const float*)d_in[4];
    const float* lng = (const float*)d_in[5];
    const float* lnb = (const float*)d_in[6];
    // d_in[7] = alpha: unused — alpha*cal_scalar is d-constant; LayerNorm cancels it exactly.
    const float* th1 = (const float*)d_in[8];
    const float* ph1 = (const float*)d_in[9];
    const float* th2 = (const float*)d_in[10];
    const float* ph2 = (const float*)d_in[11];
    const float* w1  = (const float*)d_in[12];
    const float* w2  = (const float*)d_in[13];
    const float* bg  = (const float*)d_in[14];

    float* CT   = (float*)d_ws;                    // [F][D] = 1 MB
    float* wj   = CT + (size_t)DD * FF;            // [512] weight table
    int*   nact = (int*)(wj + 512);                // active-count
    float* base = wj + 1024;                       // [2][NCMAX][BB][DD] = 67 MB
    float* outp = (float*)d_out;

    void* args[] = {
        (void*)&x, (void*)&Pw, (void*)&Ww, (void*)&Wb, (void*)&bv,
        (void*)&lng, (void*)&lnb,
        (void*)&th1, (void*)&ph1, (void*)&th2, (void*)&ph2,
        (void*)&w1, (void*)&w2, (void*)&bg,
        (void*)&CT, (void*)&wj, (void*)&nact, (void*)&base, (void*)&outp
    };
    hipLaunchCooperativeKernel((const void*)fused_all, dim3(NBLK), dim3(NTHR),
                               args, 0, stream);
}

// Round 9
// 99.911 us; speedup vs baseline: 1.8386x; 1.8386x over previous
//
#include <hip/hip_runtime.h>

// Problem constants (fixed by the reference).
#define BB   32
#define TT   2048
#define FF   512
#define KK   1024
#define DD   512
#define NSLOT 64         // c-slot parallelism; block loops c = slot + 64j
#define LN_EPS 1e-5f
#define WCUT 1e-12f      // drop terms with EMA weight < 1e-12 (bounded err ~5e-11 << 5.8e-2 thr)

typedef __attribute__((ext_vector_type(8))) short bf16x8;
typedef __attribute__((ext_vector_type(4))) float f32x4;

// g = clip(sigmoid(w1*cos(t1)cos(p1) + w2*cos(t2)cos(p2) + b_g), 0.05, 0.75)
__device__ __forceinline__ float compute_g(const float* th1, const float* ph1,
                                           const float* th2, const float* ph2,
                                           const float* w1, const float* w2,
                                           const float* bg) {
    float z1 = cosf(*th1) * cosf(*ph1);
    float z2 = cosf(*th2) * cosf(*ph2);
    float s  = (*w1) * z1 + (*w2) * z2 + (*bg);
    float sg = 1.0f / (1.0f + expf(-s));
    return fminf(fmaxf(sg, 0.05f), 0.75f);
}

// fp32 -> bf16 bits, round-to-nearest-even
__device__ __forceinline__ ushort f2bf(float x) {
    unsigned u = __float_as_uint(x);
    u += 0x7FFFu + ((u >> 16) & 1u);
    return (ushort)(u >> 16);
}

// ---- MFMA weight merge: CT[f][d] = sum_k Ww[d][k] * Pw[k][f] (bf16 in, fp32 acc). ----
// VERIFIED in rounds 7/8 (absmax 0.0156 vs 5.8e-2 threshold). 64 blocks (8x8 of
// 64d x 64f tiles), 256 threads = 4 waves (2x2, each 32x32 output). Octet-major
// XOR-slot LDS layout, identical for A and B (any k-order assumption cancels).
// Block 0 also precomputes wj[c] = g*(1-g)^c, n_active, and zeroes the bg counters.
__global__ __launch_bounds__(256) void weight_merge(
    const float* __restrict__ Pw, const float* __restrict__ Ww,
    float* __restrict__ CT, float* __restrict__ wj, int* __restrict__ nact,
    int* __restrict__ cnt,
    const float* th1, const float* ph1, const float* th2, const float* ph2,
    const float* w1p, const float* w2p, const float* bgp) {

    __shared__ __align__(16) ushort As[8 * 64 * 8];   // Ww tile, 8 KB
    __shared__ __align__(16) ushort Bs[8 * 64 * 8];   // Pw^T tile, 8 KB
    __shared__ int cnt4[4];

    const int tid = threadIdx.x;

    // ---- setup prelude: only block 0. ----
    if (blockIdx.x == 0) {
        if (tid < 8) cnt[tid] = 0;       // reset finisher counters EVERY launch
        const float g   = compute_g(th1, ph1, th2, ph2, w1p, w2p, bgp);
        const float omg = 1.0f - g;
        const float w0  = g * powf(omg, (float)tid);
        const float w1  = g * powf(omg, (float)(tid + 256));
        wj[tid]       = w0;
        wj[tid + 256] = w1;
        const unsigned long long m0 = __ballot(w0 >= WCUT);
        const unsigned long long m1 = __ballot(w1 >= WCUT);
        if ((tid & 63) == 0) cnt4[tid >> 6] = __popcll(m0) + __popcll(m1);
        __syncthreads();
        if (tid == 0) *nact = cnt4[0] + cnt4[1] + cnt4[2] + cnt4[3];
    }

    const int d0   = (blockIdx.x >> 3) * 64;
    const int f0   = (blockIdx.x & 7) * 64;
    const int wave = tid >> 6;
    const int lane = tid & 63;
    const int wm2  = wave >> 1;        // wave's d-half
    const int wn2  = wave & 1;         // wave's f-half
    const int lg   = lane >> 4;        // k-octet group 0..3
    const int ll   = lane & 15;        // free-index lane

    const int cw = tid & 15;           // staging: column group
    const int rq = tid >> 4;           // staging: row group

    f32x4 acc00 = {0.f, 0.f, 0.f, 0.f}, acc01 = {0.f, 0.f, 0.f, 0.f};
    f32x4 acc10 = {0.f, 0.f, 0.f, 0.f}, acc11 = {0.f, 0.f, 0.f, 0.f};

    float4 wwreg[4], pwa[2], pwb[2];

#define STAGE_LOAD(kkv) do {                                                          \
        _Pragma("unroll")                                                             \
        for (int i = 0; i < 4; ++i)                                                   \
            wwreg[i] = *(const float4*)(Ww + (size_t)(d0 + rq + i * 16) * KK + (kkv) + cw * 4); \
        _Pragma("unroll")                                                             \
        for (int i = 0; i < 2; ++i) {                                                 \
            const int kr = (rq + i * 16) * 2;                                         \
            pwa[i] = *(const float4*)(Pw + (size_t)((kkv) + kr)     * FF + f0 + cw * 4); \
            pwb[i] = *(const float4*)(Pw + (size_t)((kkv) + kr + 1) * FF + f0 + cw * 4); \
        }                                                                             \
    } while (0)

    STAGE_LOAD(0);

    for (int kk = 0; kk < KK; kk += 64) {
        // ---- convert + write LDS (from regs) ----
        {
            const int qa = cw >> 1, ha = cw & 1;
            #pragma unroll
            for (int i = 0; i < 4; ++i) {
                const int r = rq + i * 16;
                ushort4 b;
                b.x = f2bf(wwreg[i].x); b.y = f2bf(wwreg[i].y);
                b.z = f2bf(wwreg[i].z); b.w = f2bf(wwreg[i].w);
                *(ushort4*)&As[qa * 512 + ((r ^ (qa & 3)) << 3) + ha * 4] = b;
            }
            #pragma unroll
            for (int i = 0; i < 2; ++i) {
                const int kr = (rq + i * 16) * 2;
                const int q  = kr >> 3, j = kr & 7, q3 = q & 3;
                const float fa[4] = {pwa[i].x, pwa[i].y, pwa[i].z, pwa[i].w};
                const float fb[4] = {pwb[i].x, pwb[i].y, pwb[i].z, pwb[i].w};
                #pragma unroll
                for (int e = 0; e < 4; ++e) {
                    ushort2 p; p.x = f2bf(fa[e]); p.y = f2bf(fb[e]);
                    *(ushort2*)&Bs[q * 512 + (((cw * 4 + e) ^ q3) << 3) + j] = p;
                }
            }
        }
        __syncthreads();

        if (kk + 64 < KK) STAGE_LOAD(kk + 64);   // prefetch next chunk under compute

        #pragma unroll
        for (int ks = 0; ks < 2; ++ks) {
            const int base = (ks * 4 + lg) * 512;
            const bf16x8 af0 = *(const bf16x8*)&As[base + (((wm2 * 32 +  0 + ll) ^ lg) << 3)];
            const bf16x8 af1 = *(const bf16x8*)&As[base + (((wm2 * 32 + 16 + ll) ^ lg) << 3)];
            const bf16x8 bg0 = *(const bf16x8*)&Bs[base + (((wn2 * 32 +  0 + ll) ^ lg) << 3)];
            const bf16x8 bg1 = *(const bf16x8*)&Bs[base + (((wn2 * 32 + 16 + ll) ^ lg) << 3)];
            acc00 = __builtin_amdgcn_mfma_f32_16x16x32_bf16(af0, bg0, acc00, 0, 0, 0);
            acc01 = __builtin_amdgcn_mfma_f32_16x16x32_bf16(af0, bg1, acc01, 0, 0, 0);
            acc10 = __builtin_amdgcn_mfma_f32_16x16x32_bf16(af1, bg0, acc10, 0, 0, 0);
            acc11 = __builtin_amdgcn_mfma_f32_16x16x32_bf16(af1, bg1, acc11, 0, 0, 0);
        }
        __syncthreads();
    }
#undef STAGE_LOAD

    // epilogue: CT[f][d] (D-layout HW-verified: col=lane&15 -> f, row=(lane>>4)*4+reg -> d)
    {
        const int fb = f0 + wn2 * 32 + ll;
        const int db = d0 + wm2 * 32 + lg * 4;
        *(float4*)(CT + (size_t)(fb     ) * DD + db     ) = make_float4(acc00[0], acc00[1], acc00[2], acc00[3]);
        *(float4*)(CT + (size_t)(fb + 16) * DD + db     ) = make_float4(acc01[0], acc01[1], acc01[2], acc01[3]);
        *(float4*)(CT + (size_t)(fb     ) * DD + db + 16) = make_float4(acc10[0], acc10[1], acc10[2], acc10[3]);
        *(float4*)(CT + (size_t)(fb + 16) * DD + db + 16) = make_float4(acc11[0], acc11[1], acc11[2], acc11[3]);
    }
}

// ---- fused base GEMM + LayerNorm + EMA + final reduce (last-block-per-bg). ----
// Grid (NSLOT=64, 8): block (cslot, bg) owns 4 batch rows [bg*4..bg*4+4), loops
// c = cslot + 64j < n_active. Per c: full 512-d base row via 4 f-slices (coalesced
// CT reads, LDS k-reduce), in-block LN (E[x^2]-mu^2), EMA-weighted accumulate in
// registers. Writes one partial row-set; the LAST block per bg (device-scope atomic
// counter, no spinning -> no deadlock) sums all slots in FIXED ascending order.
// alpha*cal_scalar is d-constant -> cancels exactly in LN -> never computed.
__global__ __launch_bounds__(512) void fused_bln(
    const float* __restrict__ x,   const float* __restrict__ CT,
    const float* __restrict__ Wb,  const float* __restrict__ bvec,
    const float* __restrict__ lng, const float* __restrict__ lnb,
    const float* __restrict__ wj,  const int* __restrict__ nact,
    float* __restrict__ partial,   int* __restrict__ cnt,
    float* __restrict__ out) {

    const int nv    = *nact;
    const int nslot = nv < NSLOT ? nv : NSLOT;
    const int cslot = blockIdx.x;
    if (cslot >= nslot) return;
    const int bg = blockIdx.y;

    __shared__ float xs[4][FF];        // 8 KB
    __shared__ float red[4][4][DD];    // 32 KB [f-slice][row][d]
    __shared__ float redw[8][4][2];    // LN wave partials
    __shared__ int   lastFlag;

    const int tid = threadIdx.x;
    const int fs  = tid >> 7;          // f-slice 0..3 (128 f each)
    const int dq  = tid & 127;         // d-quad
    const int wv  = tid >> 6;
    const int ln_ = tid & 63;

    const float bias = Wb[tid] + bvec[tid];
    const float gam  = lng[tid];
    const float bet  = lnb[tid];

    float hacc[4] = {0.f, 0.f, 0.f, 0.f};

    for (int c = cslot; c < nv; c += NSLOT) {
        const int t = TT - 1 - c;
        const float wjc = wj[c];

        // stage 4 x rows: 512 float4 = 512 threads x 1
        {
            const int r  = tid >> 7;
            const int f4 = (tid & 127) * 4;
            *(float4*)&xs[r][f4] =
                *(const float4*)(x + ((size_t)(bg * 4 + r) * TT + t) * FF + f4);
        }
        __syncthreads();

        // GEMM: this thread's f-slice (128 f) x 4 d x 4 rows. Coalesced CT float4.
        float4 a0 = {0.f,0.f,0.f,0.f}, a1 = {0.f,0.f,0.f,0.f};
        float4 a2 = {0.f,0.f,0.f,0.f}, a3 = {0.f,0.f,0.f,0.f};
        {
            const float* ctp = CT + (size_t)(fs * 128) * DD + dq * 4;
            const float* xr0 = &xs[0][fs * 128];
            const float* xr1 = &xs[1][fs * 128];
            const float* xr2 = &xs[2][fs * 128];
            const float* xr3 = &xs[3][fs * 128];
            #pragma unroll 2
            for (int f = 0; f < 128; f += 4) {
                const float4 cv0 = *(const float4*)(ctp + (size_t)(f + 0) * DD);
                const float4 cv1 = *(const float4*)(ctp + (size_t)(f + 1) * DD);
                const float4 cv2 = *(const float4*)(ctp + (size_t)(f + 2) * DD);
                const float4 cv3 = *(const float4*)(ctp + (size_t)(f + 3) * DD);
                const float4 x0 = *(const float4*)(xr0 + f);
                const float4 x1 = *(const float4*)(xr1 + f);
                const float4 x2 = *(const float4*)(xr2 + f);
                const float4 x3 = *(const float4*)(xr3 + f);
                a0.x += x0.x*cv0.x + x0.y*cv1.x + x0.z*cv2.x + x0.w*cv3.x;
                a0.y += x0.x*cv0.y + x0.y*cv1.y + x0.z*cv2.y + x0.w*cv3.y;
                a0.z += x0.x*cv0.z + x0.y*cv1.z + x0.z*cv2.z + x0.w*cv3.z;
                a0.w += x0.x*cv0.w + x0.y*cv1.w + x0.z*cv2.w + x0.w*cv3.w;
                a1.x += x1.x*cv0.x + x1.y*cv1.x + x1.z*cv2.x + x1.w*cv3.x;
                a1.y += x1.x*cv0.y + x1.y*cv1.y + x1.z*cv2.y + x1.w*cv3.y;
                a1.z += x1.x*cv0.z + x1.y*cv1.z + x1.z*cv2.z + x1.w*cv3.z;
                a1.w += x1.x*cv0.w + x1.y*cv1.w + x1.z*cv2.w + x1.w*cv3.w;
                a2.x += x2.x*cv0.x + x2.y*cv1.x + x2.z*cv2.x + x2.w*cv3.x;
                a2.y += x2.x*cv0.y + x2.y*cv1.y + x2.z*cv2.y + x2.w*cv3.y;
                a2.z += x2.x*cv0.z + x2.y*cv1.z + x2.z*cv2.z + x2.w*cv3.z;
                a2.w += x2.x*cv0.w + x2.y*cv1.w + x2.z*cv2.w + x2.w*cv3.w;
                a3.x += x3.x*cv0.x + x3.y*cv1.x + x3.z*cv2.x + x3.w*cv3.x;
                a3.y += x3.x*cv0.y + x3.y*cv1.y + x3.z*cv2.y + x3.w*cv3.y;
                a3.z += x3.x*cv0.z + x3.y*cv1.z + x3.z*cv2.z + x3.w*cv3.z;
                a3.w += x3.x*cv0.w + x3.y*cv1.w + x3.z*cv2.w + x3.w*cv3.w;
            }
        }
        *(float4*)&red[fs][0][dq * 4] = a0;
        *(float4*)&red[fs][1][dq * 4] = a1;
        *(float4*)&red[fs][2][dq * 4] = a2;
        *(float4*)&red[fs][3][dq * 4] = a3;
        __syncthreads();

        // k-reduce at d = tid (conflict-free: lanes stride 4B) + LN + EMA
        float v[4];
        #pragma unroll
        for (int r = 0; r < 4; ++r) {
            v[r] = bias;
            #pragma unroll
            for (int q = 0; q < 4; ++q) v[r] += red[q][r][tid];
        }
        {
            float S[4], Q[4];
            #pragma unroll
            for (int r = 0; r < 4; ++r) { S[r] = v[r]; Q[r] = v[r] * v[r]; }
            #pragma unroll
            for (int off = 32; off >= 1; off >>= 1) {
                #pragma unroll
                for (int r = 0; r < 4; ++r) {
                    S[r] += __shfl_xor(S[r], off);
                    Q[r] += __shfl_xor(Q[r], off);
                }
            }
            if (ln_ == 0) {
                #pragma unroll
                for (int r = 0; r < 4; ++r) { redw[wv][r][0] = S[r]; redw[wv][r][1] = Q[r]; }
            }
            __syncthreads();
            #pragma unroll
            for (int r = 0; r < 4; ++r) {
                float SS = 0.f, QQ = 0.f;
                #pragma unroll
                for (int q = 0; q < 8; ++q) { SS += redw[q][r][0]; QQ += redw[q][r][1]; }
                const float mu   = SS * (1.0f / DD);
                const float rstd = rsqrtf(QQ * (1.0f / DD) - mu * mu + LN_EPS);
                hacc[r] += wjc * ((v[r] - mu) * rstd * gam + bet);
            }
        }
        __syncthreads();   // protect xs/red/redw for next c
    }

    // ---- publish partial rows ----
    #pragma unroll
    for (int r = 0; r < 4; ++r)
        partial[((size_t)cslot * BB + bg * 4 + r) * DD + tid] = hacc[r];

    __threadfence();       // device-scope release of partial writes
    __syncthreads();
    if (tid == 0) {
        const int old = atomicAdd(&cnt[bg], 1);
        lastFlag = (old == nslot - 1);
    }
    __syncthreads();
    if (!lastFlag) return;

    // ---- finisher: fixed-order (ascending slot) sum -> deterministic ----
    __threadfence();       // acquire: see all other blocks' partial writes
    volatile const float* vp = partial;
    #pragma unroll
    for (int r = 0; r < 4; ++r) {
        float s = 0.f;
        for (int cs = 0; cs < nslot; ++cs)
            s += vp[((size_t)cs * BB + bg * 4 + r) * DD + tid];
        out[(size_t)(bg * 4 + r) * DD + tid] = s;
    }
}

extern "C" void kernel_launch(void* const* d_in, const int* in_sizes, int n_in,
                              void* d_out, int out_size, void* d_ws, size_t ws_size,
                              hipStream_t stream) {
    const float* x   = (const float*)d_in[0];
    const float* Pw  = (const float*)d_in[1];
    const float* Ww  = (const float*)d_in[2];
    const float* Wb  = (const float*)d_in[3];
    const float* bv  = (const float*)d_in[4];
    const float* lng = (const float*)d_in[5];
    const float* lnb = (const float*)d_in[6];
    // d_in[7] = alpha: unused — alpha*cal_scalar is d-constant; LayerNorm cancels it exactly.
    const float* th1 = (const float*)d_in[8];
    const float* ph1 = (const float*)d_in[9];
    const float* th2 = (const float*)d_in[10];
    const float* ph2 = (const float*)d_in[11];
    const float* w1  = (const float*)d_in[12];
    const float* w2  = (const float*)d_in[13];
    const float* bg  = (const float*)d_in[14];

    float* CT      = (float*)d_ws;                 // [F][D] = 1 MB
    float* wj      = CT + (size_t)DD * FF;         // [512] weight table
    int*   nact    = (int*)(wj + 512);             // active-count
    int*   cnt     = nact + 1;                     // [8] finisher counters
    float* partial = wj + 1024;                    // [NSLOT][BB][DD] = 4 MB

    weight_merge<<<64, 256, 0, stream>>>(Pw, Ww, CT, wj, nact, cnt,
                                         th1, ph1, th2, ph2, w1, w2, bg);

    dim3 grid(NSLOT, 8);
    fused_bln<<<grid, 512, 0, stream>>>(x, CT, Wb, bv, lng, lnb, wj, nact,
                                        partial, cnt, (float*)d_out);
}